// Round 1
// 666.157 us; speedup vs baseline: 1.0458x; 1.0458x over previous
//
#include <hip/hip_runtime.h>
#include <stdint.h>

typedef unsigned short u16;
typedef __bf16 bf16x8 __attribute__((ext_vector_type(8)));
typedef float f32x4 __attribute__((ext_vector_type(4)));
typedef float f32x16 __attribute__((ext_vector_type(16)));

__device__ __forceinline__ u16 f2b(float f) {
  union { float f; unsigned u; } v; v.f = f;
  unsigned r = v.u + 0x7fffu + ((v.u >> 16) & 1u);
  return (u16)(r >> 16);
}
__device__ __forceinline__ float b2f(u16 b) {
  union { unsigned u; float f; } v; v.u = ((unsigned)b) << 16;
  return v.f;
}

// st-swizzle for 64B-row LDS slots: flips 16B-chunk bits 4-5 with row bits.
// Gives exact 2-way bank aliasing (free) for the 16-lane fm-strided ds_read_b128.
__device__ __forceinline__ int swz64(int b) {
  return b ^ (((((b >> 6) & 3) ^ ((b >> 8) & 1))) << 4);
}

// ---------------------------------------------------------------- cast fp32 -> bf16
__global__ __launch_bounds__(256) void cast_bf16(const float* __restrict__ in,
                                                 u16* __restrict__ out, int n4) {
  int i = blockIdx.x * 256 + threadIdx.x;
  if (i >= n4) return;
  float4 f = ((const float4*)in)[i];
  ushort4 r = make_ushort4(f2b(f.x), f2b(f.y), f2b(f.z), f2b(f.w));
  ((ushort4*)out)[i] = r;
}

// ---------------------------------------------------------------- fold fm weight into projection
// out[h*128+j, i] = sum_d fmw[j,d] * W[h*128+d, i]   (bf16 out)
__global__ __launch_bounds__(256) void fold_w(const float* __restrict__ W,
                                              const float* __restrict__ fmw,
                                              u16* __restrict__ out) {
  int hj = blockIdx.x;
  int h = hj >> 7, j = hj & 127;
  int i0 = threadIdx.x * 4;
  float a0 = 0.f, a1 = 0.f, a2 = 0.f, a3 = 0.f;
  const float* Wh = W + (size_t)(h * 128) * 1024 + i0;
  const float* fw = fmw + j * 128;
  for (int d = 0; d < 128; ++d) {
    float wv = fw[d];
    const float* wr = Wh + (size_t)d * 1024;
    a0 += wv * wr[0]; a1 += wv * wr[1]; a2 += wv * wr[2]; a3 += wv * wr[3];
  }
  ushort4 r = make_ushort4(f2b(a0), f2b(a1), f2b(a2), f2b(a3));
  ((ushort4*)(out + (size_t)hj * 1024))[threadIdx.x] = r;
}

// ---------------------------------------------------------------- 256x256 8-phase BT GEMM
// C[M,N] = A[M,K] @ B[N,K]^T, all bf16. 512 threads = 8 waves (2M x 4N),
// per-wave C = 128x64. LDS 128 KiB: A[buf2][kh2][256][32] | B same (+32768 u16).
// Per tile (BK=64): 4 phases (mh,kk); 1 half-tile stage/phase; counted vmcnt(4)
// per tile boundary (2 stages stay in flight); vmcnt(0) only at final boundary.
// Stage schedule (slot freed >=1 trailing barrier before issue):
//   p0: A-kh1(t+1)  p1: B-kh1(t+1)  p2: A-kh0(t+2)  p3: B-kh0(t+2)
__global__ __launch_bounds__(512, 2) void gemm256(const u16* __restrict__ A,
                                                  const u16* __restrict__ B,
                                                  u16* __restrict__ C,
                                                  int M, int N, int K, int LNT) {
  __shared__ u16 lds[65536];  // 128 KiB
  const int tid = threadIdx.x, w = tid >> 6, lane = tid & 63;
  int g = blockIdx.x;
  int wg = (g & 7) * ((int)gridDim.x >> 3) + (g >> 3);  // XCD swizzle (nwg%8==0)
  const int nt = wg & ((1 << LNT) - 1), mt = wg >> LNT;
  const int m0 = mt << 8, n0 = nt << 8;
  const int wm = w >> 2, wn = w & 3;
  const int fm = lane & 15, fkb = (lane >> 4) << 4;  // frag row, k byte offset

  // staging: linear LDS dest (base + lane*16), pre-swizzled global source
  int so0 = w * 1024 + lane * 16;
  int so1 = so0 + 8192;
  const int p0s = swz64(so0), p1s = swz64(so1);
  const size_t ga0 = (size_t)(p0s >> 6) * K + ((p0s & 63) >> 1);
  const size_t ga1 = (size_t)(p1s >> 6) * K + ((p1s & 63) >> 1);
  so0 >>= 1; so1 >>= 1;  // u16 offsets
#define STAGE(g0, slot)                                                               \
  do {                                                                                \
    __builtin_amdgcn_global_load_lds(                                                 \
        (const __attribute__((address_space(1))) unsigned int*)((g0) + ga0),          \
        (__attribute__((address_space(3))) unsigned int*)((slot) + so0), 16, 0, 0);   \
    __builtin_amdgcn_global_load_lds(                                                 \
        (const __attribute__((address_space(1))) unsigned int*)((g0) + ga1),          \
        (__attribute__((address_space(3))) unsigned int*)((slot) + so1), 16, 0, 0);   \
  } while (0)

  // fragment ds_read offsets (swizzled, slot-relative, u16)
  int aoff[2][4], boff[4];
#pragma unroll
  for (int mh = 0; mh < 2; ++mh)
#pragma unroll
    for (int mi = 0; mi < 4; ++mi)
      aoff[mh][mi] = swz64((wm * 128 + mh * 64 + mi * 16 + fm) * 64 + fkb) >> 1;
#pragma unroll
  for (int ni = 0; ni < 4; ++ni)
    boff[ni] = swz64((wn * 64 + ni * 16 + fm) * 64 + fkb) >> 1;

  const u16* Ag = A + (size_t)m0 * K;
  const u16* Bg = B + (size_t)n0 * K;
  const int NT = K >> 6;
  f32x4 acc[8][4] = {};

  // prologue: A0(0) B0(0) A1(0) B1(0) A0(1) B0(1); keep last 2 stages in flight
  STAGE(Ag, lds);
  STAGE(Bg, lds + 32768);
  STAGE(Ag + 32, lds + 8192);
  STAGE(Bg + 32, lds + 32768 + 8192);
  STAGE(Ag + 64, lds + 16384);
  STAGE(Bg + 64, lds + 32768 + 16384);
  asm volatile("s_waitcnt vmcnt(4)" ::: "memory");
  __builtin_amdgcn_s_barrier();

  for (int t = 0; t < NT; ++t) {
    const int buf = t & 1, nb = buf ^ 1;
    const u16* As0 = lds + buf * 16384;
    const u16* As1 = As0 + 8192;
    const u16* Bs0 = lds + 32768 + buf * 16384;
    const u16* Bs1 = Bs0 + 8192;
    bf16x8 a[4], bfr[4];

    // ---- phase 0: (mh0, kk0)
#pragma unroll
    for (int mi = 0; mi < 4; ++mi) a[mi] = *(const bf16x8*)(As0 + aoff[0][mi]);
#pragma unroll
    for (int ni = 0; ni < 4; ++ni) bfr[ni] = *(const bf16x8*)(Bs0 + boff[ni]);
    if (t + 1 < NT) STAGE(Ag + (t + 1) * 64 + 32, lds + nb * 16384 + 8192);
    __builtin_amdgcn_s_barrier();
    asm volatile("s_waitcnt lgkmcnt(0)" ::: "memory");
    __builtin_amdgcn_sched_barrier(0);
    __builtin_amdgcn_s_setprio(1);
#pragma unroll
    for (int mi = 0; mi < 4; ++mi)
#pragma unroll
      for (int ni = 0; ni < 4; ++ni)
        acc[mi][ni] = __builtin_amdgcn_mfma_f32_16x16x32_bf16(a[mi], bfr[ni], acc[mi][ni], 0, 0, 0);
    __builtin_amdgcn_s_setprio(0);
    __builtin_amdgcn_s_barrier();

    // ---- phase 1: (mh1, kk0) — reuse B frags
#pragma unroll
    for (int mi = 0; mi < 4; ++mi) a[mi] = *(const bf16x8*)(As0 + aoff[1][mi]);
    if (t + 1 < NT) STAGE(Bg + (t + 1) * 64 + 32, lds + 32768 + nb * 16384 + 8192);
    __builtin_amdgcn_s_barrier();
    asm volatile("s_waitcnt lgkmcnt(0)" ::: "memory");
    __builtin_amdgcn_sched_barrier(0);
    __builtin_amdgcn_s_setprio(1);
#pragma unroll
    for (int mi = 0; mi < 4; ++mi)
#pragma unroll
      for (int ni = 0; ni < 4; ++ni)
        acc[4 + mi][ni] =
            __builtin_amdgcn_mfma_f32_16x16x32_bf16(a[mi], bfr[ni], acc[4 + mi][ni], 0, 0, 0);
    __builtin_amdgcn_s_setprio(0);
    __builtin_amdgcn_s_barrier();

    // ---- phase 2: (mh0, kk1)
#pragma unroll
    for (int mi = 0; mi < 4; ++mi) a[mi] = *(const bf16x8*)(As1 + aoff[0][mi]);
#pragma unroll
    for (int ni = 0; ni < 4; ++ni) bfr[ni] = *(const bf16x8*)(Bs1 + boff[ni]);
    if (t + 2 < NT) STAGE(Ag + (t + 2) * 64, lds + buf * 16384);
    __builtin_amdgcn_s_barrier();
    asm volatile("s_waitcnt lgkmcnt(0)" ::: "memory");
    __builtin_amdgcn_sched_barrier(0);
    __builtin_amdgcn_s_setprio(1);
#pragma unroll
    for (int mi = 0; mi < 4; ++mi)
#pragma unroll
      for (int ni = 0; ni < 4; ++ni)
        acc[mi][ni] = __builtin_amdgcn_mfma_f32_16x16x32_bf16(a[mi], bfr[ni], acc[mi][ni], 0, 0, 0);
    __builtin_amdgcn_s_setprio(0);
    __builtin_amdgcn_s_barrier();

    // ---- phase 3: (mh1, kk1)
#pragma unroll
    for (int mi = 0; mi < 4; ++mi) a[mi] = *(const bf16x8*)(As1 + aoff[1][mi]);
    if (t + 2 < NT) STAGE(Bg + (t + 2) * 64, lds + 32768 + buf * 16384);
    __builtin_amdgcn_s_barrier();
    asm volatile("s_waitcnt lgkmcnt(0)" ::: "memory");
    __builtin_amdgcn_sched_barrier(0);
    __builtin_amdgcn_s_setprio(1);
#pragma unroll
    for (int mi = 0; mi < 4; ++mi)
#pragma unroll
      for (int ni = 0; ni < 4; ++ni)
        acc[4 + mi][ni] =
            __builtin_amdgcn_mfma_f32_16x16x32_bf16(a[mi], bfr[ni], acc[4 + mi][ni], 0, 0, 0);
    __builtin_amdgcn_s_setprio(0);
    // tile boundary: guarantee tile t+1 fully staged; keep 2 stages in flight
    if (t < NT - 2)
      asm volatile("s_waitcnt vmcnt(4)" ::: "memory");
    else
      asm volatile("s_waitcnt vmcnt(0)" ::: "memory");
    __builtin_amdgcn_s_barrier();
  }
#undef STAGE

  // ---- epilogue: stage C tile in LDS (256x256 u16 = full 128 KiB), coalesced store
  u16* Cs = lds;
  const int cr = (lane >> 4) << 2, cc = lane & 15;
#pragma unroll
  for (int am = 0; am < 8; ++am)
#pragma unroll
    for (int ni = 0; ni < 4; ++ni)
#pragma unroll
      for (int r = 0; r < 4; ++r)
        Cs[(wm * 128 + (am >> 2) * 64 + (am & 3) * 16 + cr + r) * 256 + wn * 64 + ni * 16 + cc] =
            f2b(acc[am][ni][r]);
  __syncthreads();
#pragma unroll
  for (int pass = 0; pass < 16; ++pass) {
    int row = pass * 16 + (tid >> 5);
    int colb = (tid & 31) << 4;
    *(uint4*)((char*)(C + (size_t)(m0 + row) * N + n0) + colb) =
        *(const uint4*)((const char*)(Cs + row * 256) + colb);
  }
}

// ---------------------------------------------------------------- m97-style BT GEMM
// C[M,N] = A[M,K] @ B[N,K]^T, A/B bf16, OUT_BF16 ? bf16 : fp32 output.
// SWZ=0: m-tiles sliced across XCDs (LNT = log2 n-tiles). SWZ=1: n-tiles sliced
// (for the vT GEMM, m-tiles == 8).
template <int OUT_BF16>
__global__ __launch_bounds__(256) void gemm_bt(const u16* __restrict__ A,
                                               const u16* __restrict__ B,
                                               void* __restrict__ Cv,
                                               int M, int N, int K, int SWZ, int LNT) {
  __shared__ u16 smem[16384];  // As[128*64] | Bs[128*64]; reused as C tile
  u16* As = smem;
  u16* Bs = smem + 8192;
  const int tid = threadIdx.x;
  int g = blockIdx.y * gridDim.x + blockIdx.x;
  int xcd = g & 7, local = g >> 3;
  int mt, nt;
  if (SWZ == 0) {
    mt = xcd * ((int)gridDim.y >> 3) + (local >> LNT);
    nt = local & ((1 << LNT) - 1);
  } else {
    nt = xcd * ((int)gridDim.x >> 3) + (local >> 3);
    mt = local & 7;
  }
  const int m0 = mt * 128, n0 = nt * 128;
  const int wave = tid >> 6, lane = tid & 63;
  const int wm = (wave >> 1) << 6, wn = (wave & 1) << 6;
  f32x4 acc[4][4] = {};
  const int srow = tid >> 3;         // 0..31
  const int scol = (tid & 7) << 3;   // 0..56
  const u16* Ab = A + (size_t)(m0 + srow) * K + scol;
  const u16* Bb = B + (size_t)(n0 + srow) * K + scol;
  u16* Asp = As + srow * 64 + scol;
  u16* Bsp = Bs + srow * 64 + scol;
  const int fm = lane & 15;
  const int fk = (lane >> 4) << 3;
  for (int kt = 0; kt < K; kt += 64) {
#pragma unroll
    for (int i = 0; i < 4; ++i) {
      __builtin_amdgcn_global_load_lds(
          (__attribute__((address_space(1))) unsigned int*)(Ab + (size_t)i * 32 * K + kt),
          (__attribute__((address_space(3))) unsigned int*)(Asp + i * 32 * 64), 16, 0, 0);
      __builtin_amdgcn_global_load_lds(
          (__attribute__((address_space(1))) unsigned int*)(Bb + (size_t)i * 32 * K + kt),
          (__attribute__((address_space(3))) unsigned int*)(Bsp + i * 32 * 64), 16, 0, 0);
    }
    __syncthreads();
#pragma unroll
    for (int kb = 0; kb < 2; ++kb) {
      bf16x8 af[4], bfr[4];
#pragma unroll
      for (int i = 0; i < 4; ++i)
        af[i] = *(const bf16x8*)(As + (wm + i * 16 + fm) * 64 + kb * 32 + fk);
#pragma unroll
      for (int j = 0; j < 4; ++j)
        bfr[j] = *(const bf16x8*)(Bs + (wn + j * 16 + fm) * 64 + kb * 32 + fk);
#pragma unroll
      for (int i = 0; i < 4; ++i)
#pragma unroll
        for (int j = 0; j < 4; ++j)
          acc[i][j] = __builtin_amdgcn_mfma_f32_16x16x32_bf16(af[i], bfr[j], acc[i][j], 0, 0, 0);
    }
    __syncthreads();
  }
  const int cr = (lane >> 4) << 2;
  const int cc = lane & 15;
  if (OUT_BF16) {
    u16* Cs = smem;  // 128x128 u16 = 32 KiB
#pragma unroll
    for (int i = 0; i < 4; ++i)
#pragma unroll
      for (int j = 0; j < 4; ++j)
#pragma unroll
        for (int r = 0; r < 4; ++r)
          Cs[(wm + i * 16 + cr + r) * 128 + wn + j * 16 + cc] = f2b(acc[i][j][r]);
    __syncthreads();
    u16* Cg = (u16*)Cv;
#pragma unroll
    for (int i = 0; i < 8; ++i) {
      int row = (i >> 1) * 32 + (tid >> 3);
      int col = ((i & 1) * 8 + (tid & 7)) * 8;
      *(uint4*)(Cg + (size_t)(m0 + row) * N + n0 + col) = *(const uint4*)(Cs + row * 128 + col);
    }
  } else {
    float* Csf = (float*)smem;  // 64x128 f32 = 32 KiB (two half-passes)
    float* Cg = (float*)Cv;
#pragma unroll
    for (int hh = 0; hh < 2; ++hh) {
      __syncthreads();
      if ((wm >> 6) == hh) {
#pragma unroll
        for (int i = 0; i < 4; ++i)
#pragma unroll
          for (int j = 0; j < 4; ++j)
#pragma unroll
            for (int r = 0; r < 4; ++r)
              Csf[(i * 16 + cr + r) * 128 + wn + j * 16 + cc] = acc[i][j][r];
      }
      __syncthreads();
#pragma unroll
      for (int i = 0; i < 8; ++i) {
        int row = (i >> 1) * 16 + (tid >> 4);
        int col = ((i & 1) * 16 + (tid & 15)) * 4;
        *(float4*)(Cg + (size_t)(m0 + hh * 64 + row) * N + n0 + col) =
            *(const float4*)(Csf + row * 128 + col);
      }
    }
  }
}

// ---------------------------------------------------------------- hedgehog softmax
// y: [T rows][2048] (merged q|k), rowhead rh -> row rh>>3, col (rh&7)*128+colbase.
// phi: [rh][256] bf16
__global__ __launch_bounds__(256) void hedgehog_sm(const u16* __restrict__ y,
                                                   const float* __restrict__ bias,
                                                   u16* __restrict__ phi, float scale,
                                                   int colbase) {
  int wave = threadIdx.x >> 6, lane = threadIdx.x & 63;
  int rh = blockIdx.x * 4 + wave;
  const u16* yr = y + (size_t)(rh >> 3) * 2048 + colbase + (rh & 7) * 128;
  float a1 = 2.f * (b2f(yr[lane]) + bias[lane]);
  float a2 = 2.f * (b2f(yr[lane + 64]) + bias[lane + 64]);
  float mx = fmaxf(fabsf(a1), fabsf(a2));
#pragma unroll
  for (int off = 32; off; off >>= 1) mx = fmaxf(mx, __shfl_xor(mx, off, 64));
  float e1 = __expf(a1 - mx), e2 = __expf(a2 - mx);
  float n1 = __expf(-a1 - mx), n2 = __expf(-a2 - mx);
  float s = e1 + e2 + n1 + n2;
#pragma unroll
  for (int off = 32; off; off >>= 1) s += __shfl_xor(s, off, 64);
  float inv = scale / s;
  u16* pr = phi + (size_t)rh * 256;
  pr[lane] = f2b(e1 * inv);
  pr[lane + 64] = f2b(e2 * inv);
  pr[lane + 128] = f2b(n1 * inv);
  pr[lane + 192] = f2b(n2 * inv);
}

// ---------------------------------------------------------------- attention phase A, C=128
// block g: chunk n = g&63 (128 timesteps), head h = g>>6.
// intra: scores=q@k^T (frags from global), mask, At(LDS bf16), o=At@vT (vT global).
// KV[vc][d] = vT x k^T with Kt staged in LDS halves (shares At region).
__global__ __launch_bounds__(256, 1) void attn_intra_kv2(const u16* __restrict__ phi_q,
                                                         const u16* __restrict__ phi_k,
                                                         const u16* __restrict__ vt,
                                                         float* __restrict__ o,
                                                         u16* __restrict__ kv) {
  __shared__ u16 lds[18432];  // At[128][136]=17408  U  Kt[256][72]=18432
  u16* At = lds;
  u16* Kt = lds;
  int g = blockIdx.x;
  int n = g & 63, h = g >> 6;
  int t0 = n * 128;
  const u16* qg = phi_q + ((size_t)t0 * 8 + h) * 256;  // row stride 2048
  const u16* kg = phi_k + ((size_t)t0 * 8 + h) * 256;
  const u16* vg = vt + (size_t)(h * 128) * 8192 + t0;  // vc rows, stride 8192
  int tid = threadIdx.x, lane = tid & 63, w = tid >> 6;
  const int fr = lane & 31, fg = (lane >> 5) << 3;
  const int rbase = (lane >> 5) << 2;
  const int mw = (w >> 1) << 6;  // t-half
  const int nw = (w & 1) << 6;   // t'-half (scores) / vc-half (o)

  // ---- scores
  f32x16 accS[2][2] = {};
#pragma unroll
  for (int ks = 0; ks < 16; ++ks) {
    bf16x8 a[2], b[2];
#pragma unroll
    for (int i = 0; i < 2; ++i)
      a[i] = *(const bf16x8*)(qg + (size_t)(mw + i * 32 + fr) * 2048 + ks * 16 + fg);
#pragma unroll
    for (int j = 0; j < 2; ++j)
      b[j] = *(const bf16x8*)(kg + (size_t)(nw + j * 32 + fr) * 2048 + ks * 16 + fg);
#pragma unroll
    for (int i = 0; i < 2; ++i)
#pragma unroll
      for (int j = 0; j < 2; ++j)
        accS[i][j] = __builtin_amdgcn_mfma_f32_32x32x16_bf16(a[i], b[j], accS[i][j], 0, 0, 0);
  }
  // ---- mask + At (causal incl diagonal)
#pragma unroll
  for (int i = 0; i < 2; ++i)
#pragma unroll
    for (int j = 0; j < 2; ++j) {
      int col = nw + j * 32 + (lane & 31);
#pragma unroll
      for (int r = 0; r < 16; ++r) {
        int row = mw + i * 32 + (r & 3) + ((r >> 2) << 3) + rbase;
        At[row * 136 + col] = f2b(col <= row ? accS[i][j][r] : 0.f);
      }
    }
  __syncthreads();
  // ---- o = At @ vT   (A = At rows t, B = vT rows vc)
  f32x16 accO[2][2] = {};
#pragma unroll
  for (int ks = 0; ks < 8; ++ks) {
    bf16x8 a[2], b[2];
#pragma unroll
    for (int i = 0; i < 2; ++i)
      a[i] = *(const bf16x8*)(At + (mw + i * 32 + fr) * 136 + ks * 16 + fg);
#pragma unroll
    for (int j = 0; j < 2; ++j)
      b[j] = *(const bf16x8*)(vg + (size_t)(nw + j * 32 + fr) * 8192 + ks * 16 + fg);
#pragma unroll
    for (int i = 0; i < 2; ++i)
#pragma unroll
      for (int j = 0; j < 2; ++j)
        accO[i][j] = __builtin_amdgcn_mfma_f32_32x32x16_bf16(a[i], b[j], accO[i][j], 0, 0, 0);
  }
  {
    float* og = o + ((size_t)t0 * 8 + h) * 128;  // row stride 1024
#pragma unroll
    for (int i = 0; i < 2; ++i)
#pragma unroll
      for (int j = 0; j < 2; ++j) {
        int vc = nw + j * 32 + (lane & 31);
#pragma unroll
        for (int r = 0; r < 16; ++r) {
          int row = mw + i * 32 + (r & 3) + ((r >> 2) << 3) + rbase;
          og[(size_t)row * 1024 + vc] = accO[i][j][r];
        }
      }
  }
  __syncthreads();  // At dead; Kt region reuse

  // ---- KV[vc][d] = sum_t' vT[vc][t'] k[t'][d]; wave w owns d in [w*64, w*64+64)
  const int nd = w << 6;
  f32x16 accKV[4][2] = {};
#pragma unroll
  for (int hb = 0; hb < 2; ++hb) {
    {  // stage Kt half: Kt[d 0..255][t'local 0..63] stride 72
      int r4 = (tid & 15) << 2;
      int d0 = (tid >> 4) << 4;
      u16 tmp[4][16];
#pragma unroll
      for (int r = 0; r < 4; ++r) {
        const u16* src = kg + (size_t)(hb * 64 + r4 + r) * 2048 + d0;
        *(uint4*)(tmp[r]) = *(const uint4*)src;
        *(uint4*)(tmp[r] + 8) = *(const uint4*)(src + 8);
      }
#pragma unroll
      for (int jj = 0; jj < 16; ++jj) {
        ushort4 pk = make_ushort4(tmp[0][jj], tmp[1][jj], tmp[2][jj], tmp[3][jj]);
        *(ushort4*)(Kt + (d0 + jj) * 72 + r4) = pk;
      }
    }
    __syncthreads();
#pragma unroll
    for (int ks = 0; ks < 4; ++ks) {
      bf16x8 a[4], b[2];
#pragma unroll
      for (int mi = 0; mi < 4; ++mi)
        a[mi] = *(const bf16x8*)(vg + (size_t)(mi * 32 + fr) * 8192 + hb * 64 + ks * 16 + fg);
#pragma unroll
      for (int nj = 0; nj < 2; ++nj)
        b[nj] = *(const bf16x8*)(Kt + (nd + nj * 32 + fr) * 72 + ks * 16 + fg);
#pragma unroll
      for (int mi = 0; mi < 4; ++mi)
#pragma unroll
        for (int nj = 0; nj < 2; ++nj)
          accKV[mi][nj] =
              __builtin_amdgcn_mfma_f32_32x32x16_bf16(a[mi], b[nj], accKV[mi][nj], 0, 0, 0);
    }
    __syncthreads();
  }
  {
    u16* kvg = kv + (size_t)g * 32768;
#pragma unroll
    for (int mi = 0; mi < 4; ++mi)
#pragma unroll
      for (int nj = 0; nj < 2; ++nj) {
        f32x16 acc = accKV[mi][nj];
        int d = nd + nj * 32 + (lane & 31);
#pragma unroll
        for (int r = 0; r < 16; ++r) {
          int vc = mi * 32 + (r & 3) + ((r >> 2) << 3) + rbase;
          kvg[(size_t)vc * 256 + d] = f2b(acc[r]);
        }
      }
  }
}

// ---------------------------------------------------------------- attention phase B
// in-place exclusive prefix over 64 chunk-KVs per h; 4 bf16 per thread, fp32 carry
__global__ __launch_bounds__(256) void kv_scan2(u16* __restrict__ kv) {
  int idx = blockIdx.x * 256 + threadIdx.x;  // 0..65535
  int h = idx >> 13;                         // 8192 lanes per h
  int e4 = idx & 8191;
  u16* p = kv + (size_t)h * 2097152 + (size_t)e4 * 4;
  float run[4] = {};
  for (int nn = 0; nn < 64; ++nn) {
    uint2 raw = *(const uint2*)p;
    u16* rv = (u16*)&raw;
    uint2 outw;
    u16* ov = (u16*)&outw;
#pragma unroll
    for (int i = 0; i < 4; ++i) {
      float v = b2f(rv[i]);
      ov[i] = f2b(run[i]);
      run[i] += v;
    }
    *(uint2*)p = outw;
    p += 32768;
  }
}

// ---------------------------------------------------------------- attention phase C, C=128
// o += q @ S  (S = exclusive prefix KV, [vc][d] global); zero LDS
__global__ __launch_bounds__(256, 1) void attn_inter2(const u16* __restrict__ phi_q,
                                                      const u16* __restrict__ kv,
                                                      float* __restrict__ o) {
  int g = blockIdx.x;
  int n = g & 63, h = g >> 6;
  int t0 = n * 128;
  const u16* qg = phi_q + ((size_t)t0 * 8 + h) * 256;
  const u16* sg = kv + (size_t)g * 32768;
  int tid = threadIdx.x, lane = tid & 63, w = tid >> 6;
  const int fr = lane & 31, fg = (lane >> 5) << 3;
  const int rbase = (lane >> 5) << 2;
  const int mw = (w >> 1) << 6;  // t-half
  const int nw = (w & 1) << 6;   // vc-half
  f32x16 acc[2][2] = {};
#pragma unroll
  for (int ks = 0; ks < 16; ++ks) {
    bf16x8 a[2], b[2];
#pragma unroll
    for (int i = 0; i < 2; ++i)
      a[i] = *(const bf16x8*)(qg + (size_t)(mw + i * 32 + fr) * 2048 + ks * 16 + fg);
#pragma unroll
    for (int j = 0; j < 2; ++j)
      b[j] = *(const bf16x8*)(sg + (size_t)(nw + j * 32 + fr) * 256 + ks * 16 + fg);
#pragma unroll
    for (int i = 0; i < 2; ++i)
#pragma unroll
      for (int j = 0; j < 2; ++j)
        acc[i][j] = __builtin_amdgcn_mfma_f32_32x32x16_bf16(a[i], b[j], acc[i][j], 0, 0, 0);
  }
  float* og = o + ((size_t)t0 * 8 + h) * 128;
#pragma unroll
  for (int i = 0; i < 2; ++i)
#pragma unroll
    for (int j = 0; j < 2; ++j) {
      int vc = nw + j * 32 + (lane & 31);
#pragma unroll
      for (int r = 0; r < 16; ++r) {
        int row = mw + i * 32 + (r & 3) + ((r >> 2) << 3) + rbase;
        og[(size_t)row * 1024 + vc] += acc[i][j][r];
      }
    }
}

// ---------------------------------------------------------------- rmsnorm (per 1024-dim row)
__global__ __launch_bounds__(256) void rmsnorm_k(const float* __restrict__ o,
                                                 u16* __restrict__ on) {
  __shared__ float red[4];
  int row = blockIdx.x;
  const float* orow = o + (size_t)row * 1024;
  int tid = threadIdx.x;
  float4 v = ((const float4*)orow)[tid];
  float ss = v.x * v.x + v.y * v.y + v.z * v.z + v.w * v.w;
#pragma unroll
  for (int off = 32; off; off >>= 1) ss += __shfl_xor(ss, off, 64);
  if ((tid & 63) == 0) red[tid >> 6] = ss;
  __syncthreads();
  float tot = red[0] + red[1] + red[2] + red[3];
  float rms = rsqrtf(tot * (1.f / 1024.f) + 1e-5f);
  ushort4 r = make_ushort4(f2b(v.x * rms), f2b(v.y * rms), f2b(v.z * rms), f2b(v.w * rms));
  ((ushort4*)(on + (size_t)row * 1024))[tid] = r;
}

// ---------------------------------------------------------------- launch
extern "C" void kernel_launch(void* const* d_in, const int* in_sizes, int n_in,
                              void* d_out, int out_size, void* d_ws, size_t ws_size,
                              hipStream_t stream) {
  const float* x     = (const float*)d_in[0];
  const float* Wq    = (const float*)d_in[1];
  const float* Wk    = (const float*)d_in[2];
  const float* Wv    = (const float*)d_in[3];
  const float* Wo    = (const float*)d_in[4];
  const float* fmq_w = (const float*)d_in[5];
  const float* fmq_b = (const float*)d_in[6];
  const float* fmk_w = (const float*)d_in[7];
  const float* fmk_b = (const float*)d_in[8];

  // Per-batch workspace (sequential batches; 184 MiB total, proven safe in r3/r4).
  // Aliasing: kvb[0,33.5 MiB) overlaps xb[0,16) + yb head [16,33.5) — both dead
  // before attn_intra_kv2 writes kv; onb[48,64) disjoint from kv.
  char* ws = (char*)d_ws;
  u16*   kvb  = (u16*)(ws + 0);            // 33.5 MiB (64 chunks x 8 h x 64 KiB)
  u16*   xb   = (u16*)(ws + 0);            // 16 MiB
  u16*   yb   = (u16*)(ws + 16777216);     // 32 MiB (merged q|k, [8192][2048])
  u16*   onb  = (u16*)(ws + 50331648);     // 16 MiB
  u16*   phiq = (u16*)(ws + 67108864);     // 32 MiB
  u16*   phik = (u16*)(ws + 100663296);    // 32 MiB
  u16*   vtb  = (u16*)(ws + 134217728);    // 16 MiB ([1024 vc-rows][8192 t])
  float* obuf = (float*)(ws + 150994944);  // 32 MiB
  u16*   wqkc = (u16*)(ws + 184549376);    // 4 MiB ([2048][1024]: q rows | k rows)
  u16*   wvb  = (u16*)(ws + 188743680);    // 2 MiB
  u16*   wob  = (u16*)(ws + 190840832);    // 2 MiB -> end 192937984 (184 MiB)

  // weight prep (once)
  cast_bf16<<<1024, 256, 0, stream>>>(Wv, wvb, 262144);
  cast_bf16<<<1024, 256, 0, stream>>>(Wo, wob, 262144);
  fold_w<<<1024, 256, 0, stream>>>(Wq, fmq_w, wqkc);
  fold_w<<<1024, 256, 0, stream>>>(Wk, fmk_w, wqkc + 1048576);

  for (int b = 0; b < 2; ++b) {
    const float* xsrc = x + (size_t)b * 8388608;
    float* osrc = (float*)d_out + (size_t)b * 8388608;
    cast_bf16<<<8192, 256, 0, stream>>>(xsrc, xb, 2097152);
    // merged q|k projection: [8192][2048] — 256x256 8-phase kernel (32x8 tiles)
    gemm256<<<256, 512, 0, stream>>>(xb, wqkc, yb, 8192, 2048, 1024, 3);
    hedgehog_sm<<<16384, 256, 0, stream>>>(yb, fmq_b, phiq, 0.0625f, 0);     // 256^-0.5
    hedgehog_sm<<<16384, 256, 0, stream>>>(yb, fmk_b, phik, 1.0f, 1024);
    // v^T via operand swap: C[1024][8192] = Wv @ x^T
    gemm_bt<1><<<dim3(64, 8), 256, 0, stream>>>(wvb, xb, vtb, 1024, 8192, 1024, 1, 0);
    // attention, C=128
    attn_intra_kv2<<<512, 256, 0, stream>>>(phiq, phik, vtb, obuf, kvb);
    kv_scan2<<<256, 256, 0, stream>>>(kvb);
    attn_inter2<<<512, 256, 0, stream>>>(phiq, kvb, obuf);
    // rmsnorm + output projection
    rmsnorm_k<<<8192, 256, 0, stream>>>(obuf, onb);
    gemm_bt<0><<<dim3(8, 64), 256, 0, stream>>>(onb, wob, osrc, 8192, 1024, 1024, 0, 3);
  }
}

// Round 3
// 642.098 us; speedup vs baseline: 1.0850x; 1.0375x over previous
//
#include <hip/hip_runtime.h>
#include <stdint.h>

typedef unsigned short u16;
typedef __bf16 bf16x8 __attribute__((ext_vector_type(8)));
typedef float f32x4 __attribute__((ext_vector_type(4)));
typedef float f32x16 __attribute__((ext_vector_type(16)));

__device__ __forceinline__ u16 f2b(float f) {
  union { float f; unsigned u; } v; v.f = f;
  unsigned r = v.u + 0x7fffu + ((v.u >> 16) & 1u);
  return (u16)(r >> 16);
}
__device__ __forceinline__ float b2f(u16 b) {
  union { unsigned u; float f; } v; v.u = ((unsigned)b) << 16;
  return v.f;
}

// st-swizzle for 64B-row LDS slots: flips 16B-chunk bits 4-5 with row bits.
__device__ __forceinline__ int swz64(int b) {
  return b ^ (((((b >> 6) & 3) ^ ((b >> 8) & 1))) << 4);
}

#define SB0() __builtin_amdgcn_sched_barrier(0)

// ---------------------------------------------------------------- cast fp32 -> bf16
__global__ __launch_bounds__(256) void cast_bf16(const float* __restrict__ in,
                                                 u16* __restrict__ out, int n4) {
  int i = blockIdx.x * 256 + threadIdx.x;
  if (i >= n4) return;
  float4 f = ((const float4*)in)[i];
  ushort4 r = make_ushort4(f2b(f.x), f2b(f.y), f2b(f.z), f2b(f.w));
  ((ushort4*)out)[i] = r;
}

// ---------------------------------------------------------------- fold fm weight into projection
// out[h*128+j, i] = sum_d fmw[j,d] * W[h*128+d, i]   (bf16 out)
__global__ __launch_bounds__(256) void fold_w(const float* __restrict__ W,
                                              const float* __restrict__ fmw,
                                              u16* __restrict__ out) {
  int hj = blockIdx.x;
  int h = hj >> 7, j = hj & 127;
  int i0 = threadIdx.x * 4;
  float a0 = 0.f, a1 = 0.f, a2 = 0.f, a3 = 0.f;
  const float* Wh = W + (size_t)(h * 128) * 1024 + i0;
  const float* fw = fmw + j * 128;
  for (int d = 0; d < 128; ++d) {
    float wv = fw[d];
    const float* wr = Wh + (size_t)d * 1024;
    a0 += wv * wr[0]; a1 += wv * wr[1]; a2 += wv * wr[2]; a3 += wv * wr[3];
  }
  ushort4 r = make_ushort4(f2b(a0), f2b(a1), f2b(a2), f2b(a3));
  ((ushort4*)(out + (size_t)hj * 1024))[threadIdx.x] = r;
}

// ---------------------------------------------------------------- 256x256 8-phase BT GEMM
// (unchanged from passing r1 kernel)
__global__ __launch_bounds__(512, 2) void gemm256(const u16* __restrict__ A,
                                                  const u16* __restrict__ B,
                                                  u16* __restrict__ C,
                                                  int M, int N, int K, int LNT) {
  __shared__ u16 lds[65536];  // 128 KiB
  const int tid = threadIdx.x, w = tid >> 6, lane = tid & 63;
  int g = blockIdx.x;
  int wg = (g & 7) * ((int)gridDim.x >> 3) + (g >> 3);  // XCD swizzle (nwg%8==0)
  const int nt = wg & ((1 << LNT) - 1), mt = wg >> LNT;
  const int m0 = mt << 8, n0 = nt << 8;
  const int wm = w >> 2, wn = w & 3;
  const int fm = lane & 15, fkb = (lane >> 4) << 4;  // frag row, k byte offset

  int so0 = w * 1024 + lane * 16;
  int so1 = so0 + 8192;
  const int p0s = swz64(so0), p1s = swz64(so1);
  const size_t ga0 = (size_t)(p0s >> 6) * K + ((p0s & 63) >> 1);
  const size_t ga1 = (size_t)(p1s >> 6) * K + ((p1s & 63) >> 1);
  so0 >>= 1; so1 >>= 1;  // u16 offsets
#define STAGE(g0, slot)                                                               \
  do {                                                                                \
    __builtin_amdgcn_global_load_lds(                                                 \
        (const __attribute__((address_space(1))) unsigned int*)((g0) + ga0),          \
        (__attribute__((address_space(3))) unsigned int*)((slot) + so0), 16, 0, 0);   \
    __builtin_amdgcn_global_load_lds(                                                 \
        (const __attribute__((address_space(1))) unsigned int*)((g0) + ga1),          \
        (__attribute__((address_space(3))) unsigned int*)((slot) + so1), 16, 0, 0);   \
  } while (0)

  int aoff[2][4], boff[4];
#pragma unroll
  for (int mh = 0; mh < 2; ++mh)
#pragma unroll
    for (int mi = 0; mi < 4; ++mi)
      aoff[mh][mi] = swz64((wm * 128 + mh * 64 + mi * 16 + fm) * 64 + fkb) >> 1;
#pragma unroll
  for (int ni = 0; ni < 4; ++ni)
    boff[ni] = swz64((wn * 64 + ni * 16 + fm) * 64 + fkb) >> 1;

  const u16* Ag = A + (size_t)m0 * K;
  const u16* Bg = B + (size_t)n0 * K;
  const int NT = K >> 6;
  f32x4 acc[8][4] = {};

  STAGE(Ag, lds);
  STAGE(Bg, lds + 32768);
  STAGE(Ag + 32, lds + 8192);
  STAGE(Bg + 32, lds + 32768 + 8192);
  STAGE(Ag + 64, lds + 16384);
  STAGE(Bg + 64, lds + 32768 + 16384);
  asm volatile("s_waitcnt vmcnt(4)" ::: "memory");
  __builtin_amdgcn_s_barrier();

  for (int t = 0; t < NT; ++t) {
    const int buf = t & 1, nb = buf ^ 1;
    const u16* As0 = lds + buf * 16384;
    const u16* As1 = As0 + 8192;
    const u16* Bs0 = lds + 32768 + buf * 16384;
    const u16* Bs1 = Bs0 + 8192;
    bf16x8 a[4], bfr[4];

    // ---- phase 0: (mh0, kk0)
#pragma unroll
    for (int mi = 0; mi < 4; ++mi) a[mi] = *(const bf16x8*)(As0 + aoff[0][mi]);
#pragma unroll
    for (int ni = 0; ni < 4; ++ni) bfr[ni] = *(const bf16x8*)(Bs0 + boff[ni]);
    if (t + 1 < NT) STAGE(Ag + (t + 1) * 64 + 32, lds + nb * 16384 + 8192);
    __builtin_amdgcn_s_barrier();
    asm volatile("s_waitcnt lgkmcnt(0)" ::: "memory");
    SB0();
    __builtin_amdgcn_s_setprio(1);
#pragma unroll
    for (int mi = 0; mi < 4; ++mi)
#pragma unroll
      for (int ni = 0; ni < 4; ++ni)
        acc[mi][ni] = __builtin_amdgcn_mfma_f32_16x16x32_bf16(a[mi], bfr[ni], acc[mi][ni], 0, 0, 0);
    __builtin_amdgcn_s_setprio(0);
    __builtin_amdgcn_s_barrier();

    // ---- phase 1: (mh1, kk0)
#pragma unroll
    for (int mi = 0; mi < 4; ++mi) a[mi] = *(const bf16x8*)(As0 + aoff[1][mi]);
    if (t + 1 < NT) STAGE(Bg + (t + 1) * 64 + 32, lds + 32768 + nb * 16384 + 8192);
    __builtin_amdgcn_s_barrier();
    asm volatile("s_waitcnt lgkmcnt(0)" ::: "memory");
    SB0();
    __builtin_amdgcn_s_setprio(1);
#pragma unroll
    for (int mi = 0; mi < 4; ++mi)
#pragma unroll
      for (int ni = 0; ni < 4; ++ni)
        acc[4 + mi][ni] =
            __builtin_amdgcn_mfma_f32_16x16x32_bf16(a[mi], bfr[ni], acc[4 + mi][ni], 0, 0, 0);
    __builtin_amdgcn_s_setprio(0);
    __builtin_amdgcn_s_barrier();

    // ---- phase 2: (mh0, kk1)
#pragma unroll
    for (int mi = 0; mi < 4; ++mi) a[mi] = *(const bf16x8*)(As1 + aoff[0][mi]);
#pragma unroll
    for (int ni = 0; ni < 4; ++ni) bfr[ni] = *(const bf16x8*)(Bs1 + boff[ni]);
    if (t + 2 < NT) STAGE(Ag + (t + 2) * 64, lds + buf * 16384);
    __builtin_amdgcn_s_barrier();
    asm volatile("s_waitcnt lgkmcnt(0)" ::: "memory");
    SB0();
    __builtin_amdgcn_s_setprio(1);
#pragma unroll
    for (int mi = 0; mi < 4; ++mi)
#pragma unroll
      for (int ni = 0; ni < 4; ++ni)
        acc[mi][ni] = __builtin_amdgcn_mfma_f32_16x16x32_bf16(a[mi], bfr[ni], acc[mi][ni], 0, 0, 0);
    __builtin_amdgcn_s_setprio(0);
    __builtin_amdgcn_s_barrier();

    // ---- phase 3: (mh1, kk1)
#pragma unroll
    for (int mi = 0; mi < 4; ++mi) a[mi] = *(const bf16x8*)(As1 + aoff[1][mi]);
    if (t + 2 < NT) STAGE(Bg + (t + 2) * 64, lds + 32768 + buf * 16384);
    __builtin_amdgcn_s_barrier();
    asm volatile("s_waitcnt lgkmcnt(0)" ::: "memory");
    SB0();
    __builtin_amdgcn_s_setprio(1);
#pragma unroll
    for (int mi = 0; mi < 4; ++mi)
#pragma unroll
      for (int ni = 0; ni < 4; ++ni)
        acc[4 + mi][ni] =
            __builtin_amdgcn_mfma_f32_16x16x32_bf16(a[mi], bfr[ni], acc[4 + mi][ni], 0, 0, 0);
    __builtin_amdgcn_s_setprio(0);
    if (t < NT - 2)
      asm volatile("s_waitcnt vmcnt(4)" ::: "memory");
    else
      asm volatile("s_waitcnt vmcnt(0)" ::: "memory");
    __builtin_amdgcn_s_barrier();
  }
#undef STAGE

  // ---- epilogue
  u16* Cs = lds;
  const int cr = (lane >> 4) << 2, cc = lane & 15;
#pragma unroll
  for (int am = 0; am < 8; ++am)
#pragma unroll
    for (int ni = 0; ni < 4; ++ni)
#pragma unroll
      for (int r = 0; r < 4; ++r)
        Cs[(wm * 128 + (am >> 2) * 64 + (am & 3) * 16 + cr + r) * 256 + wn * 64 + ni * 16 + cc] =
            f2b(acc[am][ni][r]);
  __syncthreads();
#pragma unroll
  for (int pass = 0; pass < 16; ++pass) {
    int row = pass * 16 + (tid >> 5);
    int colb = (tid & 31) << 4;
    *(uint4*)((char*)(C + (size_t)(m0 + row) * N + n0) + colb) =
        *(const uint4*)((const char*)(Cs + row * 256) + colb);
  }
}

// ---------------------------------------------------------------- m97-style BT GEMM
template <int OUT_BF16>
__global__ __launch_bounds__(256) void gemm_bt(const u16* __restrict__ A,
                                               const u16* __restrict__ B,
                                               void* __restrict__ Cv,
                                               int M, int N, int K, int SWZ, int LNT) {
  __shared__ u16 smem[16384];  // As[128*64] | Bs[128*64]; reused as C tile
  u16* As = smem;
  u16* Bs = smem + 8192;
  const int tid = threadIdx.x;
  int g = blockIdx.y * gridDim.x + blockIdx.x;
  int xcd = g & 7, local = g >> 3;
  int mt, nt;
  if (SWZ == 0) {
    mt = xcd * ((int)gridDim.y >> 3) + (local >> LNT);
    nt = local & ((1 << LNT) - 1);
  } else {
    nt = xcd * ((int)gridDim.x >> 3) + (local >> 3);
    mt = local & 7;
  }
  const int m0 = mt * 128, n0 = nt * 128;
  const int wave = tid >> 6, lane = tid & 63;
  const int wm = (wave >> 1) << 6, wn = (wave & 1) << 6;
  f32x4 acc[4][4] = {};
  const int srow = tid >> 3;         // 0..31
  const int scol = (tid & 7) << 3;   // 0..56
  const u16* Ab = A + (size_t)(m0 + srow) * K + scol;
  const u16* Bb = B + (size_t)(n0 + srow) * K + scol;
  u16* Asp = As + srow * 64 + scol;
  u16* Bsp = Bs + srow * 64 + scol;
  const int fm = lane & 15;
  const int fk = (lane >> 4) << 3;
  for (int kt = 0; kt < K; kt += 64) {
#pragma unroll
    for (int i = 0; i < 4; ++i) {
      __builtin_amdgcn_global_load_lds(
          (__attribute__((address_space(1))) unsigned int*)(Ab + (size_t)i * 32 * K + kt),
          (__attribute__((address_space(3))) unsigned int*)(Asp + i * 32 * 64), 16, 0, 0);
      __builtin_amdgcn_global_load_lds(
          (__attribute__((address_space(1))) unsigned int*)(Bb + (size_t)i * 32 * K + kt),
          (__attribute__((address_space(3))) unsigned int*)(Bsp + i * 32 * 64), 16, 0, 0);
    }
    __syncthreads();
#pragma unroll
    for (int kb = 0; kb < 2; ++kb) {
      bf16x8 af[4], bfr[4];
#pragma unroll
      for (int i = 0; i < 4; ++i)
        af[i] = *(const bf16x8*)(As + (wm + i * 16 + fm) * 64 + kb * 32 + fk);
#pragma unroll
      for (int j = 0; j < 4; ++j)
        bfr[j] = *(const bf16x8*)(Bs + (wn + j * 16 + fm) * 64 + kb * 32 + fk);
#pragma unroll
      for (int i = 0; i < 4; ++i)
#pragma unroll
        for (int j = 0; j < 4; ++j)
          acc[i][j] = __builtin_amdgcn_mfma_f32_16x16x32_bf16(af[i], bfr[j], acc[i][j], 0, 0, 0);
    }
    __syncthreads();
  }
  const int cr = (lane >> 4) << 2;
  const int cc = lane & 15;
  if (OUT_BF16) {
    u16* Cs = smem;  // 128x128 u16 = 32 KiB
#pragma unroll
    for (int i = 0; i < 4; ++i)
#pragma unroll
      for (int j = 0; j < 4; ++j)
#pragma unroll
        for (int r = 0; r < 4; ++r)
          Cs[(wm + i * 16 + cr + r) * 128 + wn + j * 16 + cc] = f2b(acc[i][j][r]);
    __syncthreads();
    u16* Cg = (u16*)Cv;
#pragma unroll
    for (int i = 0; i < 8; ++i) {
      int row = (i >> 1) * 32 + (tid >> 3);
      int col = ((i & 1) * 8 + (tid & 7)) * 8;
      *(uint4*)(Cg + (size_t)(m0 + row) * N + n0 + col) = *(const uint4*)(Cs + row * 128 + col);
    }
  } else {
    float* Csf = (float*)smem;  // 64x128 f32 = 32 KiB (two half-passes)
    float* Cg = (float*)Cv;
#pragma unroll
    for (int hh = 0; hh < 2; ++hh) {
      __syncthreads();
      if ((wm >> 6) == hh) {
#pragma unroll
        for (int i = 0; i < 4; ++i)
#pragma unroll
          for (int j = 0; j < 4; ++j)
#pragma unroll
            for (int r = 0; r < 4; ++r)
              Csf[(i * 16 + cr + r) * 128 + wn + j * 16 + cc] = acc[i][j][r];
      }
      __syncthreads();
#pragma unroll
      for (int i = 0; i < 8; ++i) {
        int row = (i >> 1) * 16 + (tid >> 4);
        int col = ((i & 1) * 16 + (tid & 15)) * 4;
        *(float4*)(Cg + (size_t)(m0 + hh * 64 + row) * N + n0 + col) =
            *(const float4*)(Csf + row * 128 + col);
      }
    }
  }
}

// ---------------------------------------------------------------- hedgehog softmax
__global__ __launch_bounds__(256) void hedgehog_sm(const u16* __restrict__ y,
                                                   const float* __restrict__ bias,
                                                   u16* __restrict__ phi, float scale,
                                                   int colbase) {
  int wave = threadIdx.x >> 6, lane = threadIdx.x & 63;
  int rh = blockIdx.x * 4 + wave;
  const u16* yr = y + (size_t)(rh >> 3) * 2048 + colbase + (rh & 7) * 128;
  float a1 = 2.f * (b2f(yr[lane]) + bias[lane]);
  float a2 = 2.f * (b2f(yr[lane + 64]) + bias[lane + 64]);
  float mx = fmaxf(fabsf(a1), fabsf(a2));
#pragma unroll
  for (int off = 32; off; off >>= 1) mx = fmaxf(mx, __shfl_xor(mx, off, 64));
  float e1 = __expf(a1 - mx), e2 = __expf(a2 - mx);
  float n1 = __expf(-a1 - mx), n2 = __expf(-a2 - mx);
  float s = e1 + e2 + n1 + n2;
#pragma unroll
  for (int off = 32; off; off >>= 1) s += __shfl_xor(s, off, 64);
  float inv = scale / s;
  u16* pr = phi + (size_t)rh * 256;
  pr[lane] = f2b(e1 * inv);
  pr[lane + 64] = f2b(e2 * inv);
  pr[lane + 128] = f2b(n1 * inv);
  pr[lane + 192] = f2b(n2 * inv);
}

// ---------------------------------------------------------------- fused attention phase A, C=128
// 128 KiB LDS (proven size): Ks[128][256] swz | Vs[128][128] swz | R3 (32 KiB)
// time-shared: Qh[128][128] swz (two passes) -> At[128][128] swz -> Kt[256][64] swz8.
// Swizzle: LDS[row][p] = global[row][p ^ xm], xm = (row&15)<<3 (Ks/Vs/Qh/At) or
// (row&7)<<3 (Kt). All b128 reads use col multiples of 8 so (col^xm)+t=(col+t)^xm.
__global__ __launch_bounds__(256, 1) void attn_fused(const u16* __restrict__ phi_q,
                                                     const u16* __restrict__ phi_k,
                                                     const u16* __restrict__ vt,
                                                     float* __restrict__ o,
                                                     u16* __restrict__ kv) {
  __shared__ u16 lds[65536];  // 128 KiB
  u16* Ks = lds;              // [0, 32768)
  u16* Vs = lds + 32768;      // [32768, 49152)
  u16* Qh = lds + 49152;      // [49152, 65536) time-shared
  u16* At = lds + 49152;
  u16* Kt = lds + 49152;
  int g = blockIdx.x;
  int n = g & 63, h = g >> 6;
  int t0 = n * 128;
  const u16* qg = phi_q + ((size_t)t0 * 8 + h) * 256;  // row stride 2048 u16
  const u16* kg = phi_k + ((size_t)t0 * 8 + h) * 256;
  const u16* vg = vt + (size_t)(h * 128) * 8192 + t0;  // row stride 8192 u16
  int tid = threadIdx.x, lane = tid & 63, w = tid >> 6;
  const int fr = lane & 31, fg = (lane >> 5) << 3;  // frag row, k offset (u16)
  const int rbase = (lane >> 5) << 2;
  const int mw = (w >> 1) << 6;  // t-half
  const int nw = (w & 1) << 6;   // t'-half (scores) / vc-half (o)

  // ---- stage K(16), Qh0(8), V(8) via global_load_lds; pre-swizzled source
  const int c8 = (tid & 31) << 3;  // col chunk in 256-u16 rows
  const int rkq = tid >> 5;        // 0..7
  const int cv = (tid & 15) << 3;  // col chunk in 128-u16 rows
  const int rv = tid >> 4;         // 0..15
#pragma unroll
  for (int i = 0; i < 16; ++i) {
    int row = i * 8 + rkq;
    int cs = c8 ^ ((row & 15) << 3);
    __builtin_amdgcn_global_load_lds(
        (const __attribute__((address_space(1))) unsigned int*)(kg + (size_t)row * 2048 + cs),
        (__attribute__((address_space(3))) unsigned int*)(Ks + i * 2048 + tid * 8), 16, 0, 0);
  }
#pragma unroll
  for (int i = 0; i < 8; ++i) {
    int row = i * 16 + rv;
    int cs = cv ^ ((row & 15) << 3);
    __builtin_amdgcn_global_load_lds(
        (const __attribute__((address_space(1))) unsigned int*)(qg + (size_t)row * 2048 + cs),
        (__attribute__((address_space(3))) unsigned int*)(Qh + i * 2048 + tid * 8), 16, 0, 0);
  }
#pragma unroll
  for (int i = 0; i < 8; ++i) {
    int row = i * 16 + rv;
    int cs = cv ^ ((row & 15) << 3);
    __builtin_amdgcn_global_load_lds(
        (const __attribute__((address_space(1))) unsigned int*)(vg + (size_t)row * 8192 + cs),
        (__attribute__((address_space(3))) unsigned int*)(Vs + i * 2048 + tid * 8), 16, 0, 0);
  }
  asm volatile("s_waitcnt vmcnt(8)" ::: "memory");  // K,Qh0 done; V (8) in flight
  SB0(); __builtin_amdgcn_s_barrier(); SB0();

  // ---- scores = q @ k^T, two 128-wide passes (Qh restaged between)
  f32x16 accS[2][2] = {};
  const int ra0 = mw + fr, ra1 = mw + 32 + fr;
  const int rb0 = nw + fr, rb1 = nw + 32 + fr;
  const int xa0 = (ra0 & 15) << 3, xa1 = (ra1 & 15) << 3;
  const int xb0 = (rb0 & 15) << 3, xb1 = (rb1 & 15) << 3;
#pragma unroll
  for (int pass = 0; pass < 2; ++pass) {
    const int kb = pass << 7;
#pragma unroll
    for (int ks = 0; ks < 8; ++ks) {
      int col = ks * 16 + fg;  // local col in Qh; Ks col = kb + col
      bf16x8 a[2], b[2];
      a[0] = *(const bf16x8*)(Qh + ra0 * 128 + (col ^ xa0));
      a[1] = *(const bf16x8*)(Qh + ra1 * 128 + (col ^ xa1));
      b[0] = *(const bf16x8*)(Ks + rb0 * 256 + ((kb + col) ^ xb0));
      b[1] = *(const bf16x8*)(Ks + rb1 * 256 + ((kb + col) ^ xb1));
#pragma unroll
      for (int i = 0; i < 2; ++i)
#pragma unroll
        for (int j = 0; j < 2; ++j)
          accS[i][j] = __builtin_amdgcn_mfma_f32_32x32x16_bf16(a[i], b[j], accS[i][j], 0, 0, 0);
    }
    if (pass == 0) {
      asm volatile("s_waitcnt lgkmcnt(0)" ::: "memory");  // Qh0 reads retired
      SB0(); __builtin_amdgcn_s_barrier(); SB0();
#pragma unroll
      for (int i = 0; i < 8; ++i) {
        int row = i * 16 + rv;
        int cs = cv ^ ((row & 15) << 3);
        __builtin_amdgcn_global_load_lds(
            (const __attribute__((address_space(1))) unsigned int*)(qg + (size_t)row * 2048 +
                                                                    128 + cs),
            (__attribute__((address_space(3))) unsigned int*)(Qh + i * 2048 + tid * 8), 16, 0, 0);
      }
      asm volatile("s_waitcnt vmcnt(0)" ::: "memory");  // Qh1 (and V) staged
      SB0(); __builtin_amdgcn_s_barrier(); SB0();
    }
  }
  asm volatile("s_waitcnt lgkmcnt(0)" ::: "memory");
  SB0(); __builtin_amdgcn_s_barrier(); SB0();  // Qh dead -> At may overwrite

  // ---- mask + At (causal incl diagonal); At[128][128] swizzled
#pragma unroll
  for (int i = 0; i < 2; ++i)
#pragma unroll
    for (int j = 0; j < 2; ++j) {
      int col = nw + j * 32 + (lane & 31);
#pragma unroll
      for (int r = 0; r < 16; ++r) {
        int row = mw + i * 32 + (r & 3) + ((r >> 2) << 3) + rbase;
        At[row * 128 + (col ^ ((row & 15) << 3))] = f2b(col <= row ? accS[i][j][r] : 0.f);
      }
    }
  asm volatile("s_waitcnt lgkmcnt(0)" ::: "memory");
  SB0(); __builtin_amdgcn_s_barrier(); SB0();

  // ---- o = At @ vT (At + Vs from LDS)
  f32x16 accO[2][2] = {};
  {
    const int xv0 = (rb0 & 15) << 3, xv1 = (rb1 & 15) << 3;
#pragma unroll
    for (int ks = 0; ks < 8; ++ks) {
      int col = ks * 16 + fg;
      bf16x8 a[2], b[2];
      a[0] = *(const bf16x8*)(At + ra0 * 128 + (col ^ xa0));
      a[1] = *(const bf16x8*)(At + ra1 * 128 + (col ^ xa1));
      b[0] = *(const bf16x8*)(Vs + rb0 * 128 + (col ^ xv0));
      b[1] = *(const bf16x8*)(Vs + rb1 * 128 + (col ^ xv1));
#pragma unroll
      for (int i = 0; i < 2; ++i)
#pragma unroll
        for (int j = 0; j < 2; ++j)
          accO[i][j] = __builtin_amdgcn_mfma_f32_32x32x16_bf16(a[i], b[j], accO[i][j], 0, 0, 0);
    }
  }
  {
    float* og = o + ((size_t)t0 * 8 + h) * 128;  // row stride 1024
#pragma unroll
    for (int i = 0; i < 2; ++i)
#pragma unroll
      for (int j = 0; j < 2; ++j) {
        int vc = nw + j * 32 + (lane & 31);
#pragma unroll
        for (int r = 0; r < 16; ++r) {
          int row = mw + i * 32 + (r & 3) + ((r >> 2) << 3) + rbase;
          og[(size_t)row * 1024 + vc] = accO[i][j][r];
        }
      }
  }
  asm volatile("s_waitcnt lgkmcnt(0)" ::: "memory");
  SB0(); __builtin_amdgcn_s_barrier(); SB0();  // At dead -> Kt may overwrite

  // ---- KV[vc][d] = sum_t' vT[vc][t'] k[t'][d]; wave w owns d in [w*64, w*64+64)
  const int nd = w << 6;
  f32x16 accKV[4][2] = {};
#pragma unroll
  for (int hb = 0; hb < 2; ++hb) {
    {  // stage Kt half from Ks (LDS transpose): Kt[d 0..255][t' 0..63], swz8
      int r4 = (tid & 15) << 2;
      int d0 = (tid >> 4) << 4;
      u16 tmp[4][16];
#pragma unroll
      for (int r = 0; r < 4; ++r) {
        int row = hb * 64 + r4 + r;
        int xm = (row & 15) << 3;
        const u16* src = Ks + row * 256;
        *(uint4*)(tmp[r]) = *(const uint4*)(src + (d0 ^ xm));
        *(uint4*)(tmp[r] + 8) = *(const uint4*)(src + ((d0 + 8) ^ xm));
      }
#pragma unroll
      for (int jj = 0; jj < 16; ++jj) {
        ushort4 pk = make_ushort4(tmp[0][jj], tmp[1][jj], tmp[2][jj], tmp[3][jj]);
        *(ushort4*)(Kt + (d0 + jj) * 64 + (r4 ^ ((jj & 7) << 3))) = pk;
      }
    }
    asm volatile("s_waitcnt lgkmcnt(0)" ::: "memory");
    SB0(); __builtin_amdgcn_s_barrier(); SB0();
#pragma unroll
    for (int ks = 0; ks < 4; ++ks) {
      bf16x8 a[4], b[2];
#pragma unroll
      for (int mi = 0; mi < 4; ++mi) {
        int rvv = mi * 32 + fr;
        a[mi] = *(const bf16x8*)(Vs + rvv * 128 +
                                 ((hb * 64 + ks * 16 + fg) ^ ((rvv & 15) << 3)));
      }
#pragma unroll
      for (int nj = 0; nj < 2; ++nj) {
        int rk = nd + nj * 32 + fr;
        b[nj] = *(const bf16x8*)(Kt + rk * 64 + ((ks * 16 + fg) ^ ((rk & 7) << 3)));
      }
#pragma unroll
      for (int mi = 0; mi < 4; ++mi)
#pragma unroll
        for (int nj = 0; nj < 2; ++nj)
          accKV[mi][nj] =
              __builtin_amdgcn_mfma_f32_32x32x16_bf16(a[mi], b[nj], accKV[mi][nj], 0, 0, 0);
    }
    asm volatile("s_waitcnt lgkmcnt(0)" ::: "memory");
    SB0(); __builtin_amdgcn_s_barrier(); SB0();
  }
  {
    u16* kvg = kv + (size_t)g * 32768;
#pragma unroll
    for (int mi = 0; mi < 4; ++mi)
#pragma unroll
      for (int nj = 0; nj < 2; ++nj) {
        f32x16 acc = accKV[mi][nj];
        int d = nd + nj * 32 + (lane & 31);
#pragma unroll
        for (int r = 0; r < 16; ++r) {
          int vc = mi * 32 + (r & 3) + ((r >> 2) << 3) + rbase;
          kvg[(size_t)vc * 256 + d] = f2b(acc[r]);
        }
      }
  }
}

// ---------------------------------------------------------------- attention phase B
__global__ __launch_bounds__(256) void kv_scan2(u16* __restrict__ kv) {
  int idx = blockIdx.x * 256 + threadIdx.x;  // 0..65535
  int h = idx >> 13;                         // 8192 lanes per h
  int e4 = idx & 8191;
  u16* p = kv + (size_t)h * 2097152 + (size_t)e4 * 4;
  float run[4] = {};
  for (int nn = 0; nn < 64; ++nn) {
    uint2 raw = *(const uint2*)p;
    u16* rv = (u16*)&raw;
    uint2 outw;
    u16* ov = (u16*)&outw;
#pragma unroll
    for (int i = 0; i < 4; ++i) {
      float v = b2f(rv[i]);
      ov[i] = f2b(run[i]);
      run[i] += v;
    }
    *(uint2*)p = outw;
    p += 32768;
  }
}

// ---------------------------------------------------------------- attention phase C, C=128
__global__ __launch_bounds__(256, 1) void attn_inter2(const u16* __restrict__ phi_q,
                                                      const u16* __restrict__ kv,
                                                      float* __restrict__ o) {
  int g = blockIdx.x;
  int n = g & 63, h = g >> 6;
  int t0 = n * 128;
  const u16* qg = phi_q + ((size_t)t0 * 8 + h) * 256;
  const u16* sg = kv + (size_t)g * 32768;
  int tid = threadIdx.x, lane = tid & 63, w = tid >> 6;
  const int fr = lane & 31, fg = (lane >> 5) << 3;
  const int rbase = (lane >> 5) << 2;
  const int mw = (w >> 1) << 6;  // t-half
  const int nw = (w & 1) << 6;   // vc-half
  f32x16 acc[2][2] = {};
#pragma unroll
  for (int ks = 0; ks < 16; ++ks) {
    bf16x8 a[2], b[2];
#pragma unroll
    for (int i = 0; i < 2; ++i)
      a[i] = *(const bf16x8*)(qg + (size_t)(mw + i * 32 + fr) * 2048 + ks * 16 + fg);
#pragma unroll
    for (int j = 0; j < 2; ++j)
      b[j] = *(const bf16x8*)(sg + (size_t)(nw + j * 32 + fr) * 256 + ks * 16 + fg);
#pragma unroll
    for (int i = 0; i < 2; ++i)
#pragma unroll
      for (int j = 0; j < 2; ++j)
        acc[i][j] = __builtin_amdgcn_mfma_f32_32x32x16_bf16(a[i], b[j], acc[i][j], 0, 0, 0);
  }
  float* og = o + ((size_t)t0 * 8 + h) * 128;
#pragma unroll
  for (int i = 0; i < 2; ++i)
#pragma unroll
    for (int j = 0; j < 2; ++j) {
      int vc = nw + j * 32 + (lane & 31);
#pragma unroll
      for (int r = 0; r < 16; ++r) {
        int row = mw + i * 32 + (r & 3) + ((r >> 2) << 3) + rbase;
        og[(size_t)row * 1024 + vc] += acc[i][j][r];
      }
    }
}

// ---------------------------------------------------------------- rmsnorm (per 1024-dim row)
__global__ __launch_bounds__(256) void rmsnorm_k(const float* __restrict__ o,
                                                 u16* __restrict__ on) {
  __shared__ float red[4];
  int row = blockIdx.x;
  const float* orow = o + (size_t)row * 1024;
  int tid = threadIdx.x;
  float4 v = ((const float4*)orow)[tid];
  float ss = v.x * v.x + v.y * v.y + v.z * v.z + v.w * v.w;
#pragma unroll
  for (int off = 32; off; off >>= 1) ss += __shfl_xor(ss, off, 64);
  if ((tid & 63) == 0) red[tid >> 6] = ss;
  __syncthreads();
  float tot = red[0] + red[1] + red[2] + red[3];
  float rms = rsqrtf(tot * (1.f / 1024.f) + 1e-5f);
  ushort4 r = make_ushort4(f2b(v.x * rms), f2b(v.y * rms), f2b(v.z * rms), f2b(v.w * rms));
  ((ushort4*)(on + (size_t)row * 1024))[tid] = r;
}

// ---------------------------------------------------------------- launch
extern "C" void kernel_launch(void* const* d_in, const int* in_sizes, int n_in,
                              void* d_out, int out_size, void* d_ws, size_t ws_size,
                              hipStream_t stream) {
  const float* x     = (const float*)d_in[0];
  const float* Wq    = (const float*)d_in[1];
  const float* Wk    = (const float*)d_in[2];
  const float* Wv    = (const float*)d_in[3];
  const float* Wo    = (const float*)d_in[4];
  const float* fmq_w = (const float*)d_in[5];
  const float* fmq_b = (const float*)d_in[6];
  const float* fmk_w = (const float*)d_in[7];
  const float* fmk_b = (const float*)d_in[8];

  char* ws = (char*)d_ws;
  u16*   kvb  = (u16*)(ws + 0);            // 33.5 MiB (64 chunks x 8 h x 64 KiB)
  u16*   xb   = (u16*)(ws + 0);            // 16 MiB
  u16*   yb   = (u16*)(ws + 16777216);     // 32 MiB (merged q|k, [8192][2048])
  u16*   onb  = (u16*)(ws + 50331648);     // 16 MiB
  u16*   phiq = (u16*)(ws + 67108864);     // 32 MiB
  u16*   phik = (u16*)(ws + 100663296);    // 32 MiB
  u16*   vtb  = (u16*)(ws + 134217728);    // 16 MiB ([1024 vc-rows][8192 t])
  float* obuf = (float*)(ws + 150994944);  // 32 MiB
  u16*   wqkc = (u16*)(ws + 184549376);    // 4 MiB ([2048][1024]: q rows | k rows)
  u16*   wvb  = (u16*)(ws + 188743680);    // 2 MiB
  u16*   wob  = (u16*)(ws + 190840832);    // 2 MiB -> end 192937984 (184 MiB)

  // weight prep (once)
  cast_bf16<<<1024, 256, 0, stream>>>(Wv, wvb, 262144);
  cast_bf16<<<1024, 256, 0, stream>>>(Wo, wob, 262144);
  fold_w<<<1024, 256, 0, stream>>>(Wq, fmq_w, wqkc);
  fold_w<<<1024, 256, 0, stream>>>(Wk, fmk_w, wqkc + 1048576);

  for (int b = 0; b < 2; ++b) {
    const float* xsrc = x + (size_t)b * 8388608;
    float* osrc = (float*)d_out + (size_t)b * 8388608;
    cast_bf16<<<8192, 256, 0, stream>>>(xsrc, xb, 2097152);
    // merged q|k projection: [8192][2048] — 256x256 8-phase kernel (32x8 tiles)
    gemm256<<<256, 512, 0, stream>>>(xb, wqkc, yb, 8192, 2048, 1024, 3);
    hedgehog_sm<<<16384, 256, 0, stream>>>(yb, fmq_b, phiq, 0.0625f, 0);     // 256^-0.5
    hedgehog_sm<<<16384, 256, 0, stream>>>(yb, fmk_b, phik, 1.0f, 1024);
    // v^T via operand swap: C[1024][8192] = Wv @ x^T
    gemm_bt<1><<<dim3(64, 8), 256, 0, stream>>>(wvb, xb, vtb, 1024, 8192, 1024, 1, 0);
    // attention, C=128 (fully LDS-staged fused intra+KV, 128 KiB)
    attn_fused<<<512, 256, 0, stream>>>(phiq, phik, vtb, obuf, kvb);
    kv_scan2<<<256, 256, 0, stream>>>(kvb);
    attn_inter2<<<512, 256, 0, stream>>>(phiq, kvb, obuf);
    // rmsnorm + output projection
    rmsnorm_k<<<8192, 256, 0, stream>>>(obuf, onb);
    gemm_bt<0><<<dim3(8, 64), 256, 0, stream>>>(onb, wob, osrc, 8192, 1024, 1024, 0, 3);
  }
}